// Round 8
// baseline (360.309 us; speedup 1.0000x reference)
//
#include <hip/hip_runtime.h>
#include <hip/hip_bf16.h>
#include <math.h>

typedef unsigned short u16;
typedef __attribute__((ext_vector_type(8))) short short8;   // 8 bf16 (4 VGPRs)
typedef __attribute__((ext_vector_type(4))) float f32x4;

#define NB 8192
#define ND 64
// dist scale: S = exp(-dist/0.05) = exp2(-K*dist), K = 20/ln2
// We carry K^2 inside d2 so that S = exp2(-sqrt(K2*d2)).
#define K2     832.5475634f      // (20/ln2)^2
#define M2K2  -1665.0951268f     // -2*K2
#define LN2    0.69314718055994531f

#define GRID_X 128
#define GRID_Y 32
#define TOTAL_BLOCKS (GRID_X * GRID_Y)

// S from pre-scaled squared distance (d2K = K2 * dist^2)
__device__ __forceinline__ float simval2(float d2K) {
    return __builtin_amdgcn_exp2f(-__builtin_amdgcn_sqrtf(fmaxf(d2K, 0.0f)));
}

// ---------------- prep: bf16 convert, K2-scaled norms, diagS, zero accums ---
__global__ __launch_bounds__(256) void snn_prep(
    const float* __restrict__ text, const float* __restrict__ image,
    u16* __restrict__ textBf, u16* __restrict__ imageBf,
    float* __restrict__ normT, float* __restrict__ normI,
    float* __restrict__ diagS, float* __restrict__ sameSum,
    float* __restrict__ totSum, unsigned int* __restrict__ doneCnt,
    float* __restrict__ out)
{
    const int lane = threadIdx.x & 63;
    const int row  = blockIdx.x * 4 + (threadIdx.x >> 6);
    const int idx  = row * ND + lane;

    float t  = text[idx];
    float im = image[idx];
    __hip_bfloat16 tb = __float2bfloat16(t);
    __hip_bfloat16 ib = __float2bfloat16(im);
    u16 tbits, ibits;
    __builtin_memcpy(&tbits, &tb, 2);
    __builtin_memcpy(&ibits, &ib, 2);
    textBf[idx]  = tbits;
    imageBf[idx] = ibits;

    float nt = t * t;
    float ni = im * im;
    float dp = __bfloat162float(tb) * __bfloat162float(ib); // match MFMA path
    #pragma unroll
    for (int m = 32; m >= 1; m >>= 1) {
        nt += __shfl_xor(nt, m, 64);
        ni += __shfl_xor(ni, m, 64);
        dp += __shfl_xor(dp, m, 64);
    }
    if (lane == 0) {
        float snt = K2 * nt;
        float sni = K2 * ni;
        normT[row] = snt;
        normI[row] = sni;
        float d2K = fmaf(M2K2, dp, sni + snt);  // K2 * dist(image_r, text_r)^2
        diagS[row] = simval2(d2K);
        sameSum[row] = 0.0f;
        totSum[row]  = 0.0f;
        if (row == 0) { *doneCnt = 0u; out[0] = 0.0f; }
    }
}

// ---------------- main: pairwise S + grouped row sums + fused finalize ------
// Grid: (128 row-tiles, 32 col-chunks) = 4096 blocks. Block: 256 thr = 4 waves.
// Block tile: 64 rows x 256 cols. Wave: 16 rows x 256 cols, processed as
// 2 passes of an 8-column BATCH (acc[8], 2 MFMA each, loads hoisted).
// HISTORY (keep these invariants):
//  - R4 (32-row waves, acc[2][8], VGPR=104, no LDS): 51.8 us, VALUBusy 39%.
//  - R5 (batch=1 transient): VGPR 32, zero load ILP -> 131 us. The BATCH is
//    the memory ILP; never shrink it below 8 columns.
//  - R6 (LDS staging + swizzle): bank conflicts 0 but barrier+round-trip cost
//    +22 us -> direct global loads through L2 win at this reuse level.
//  - VALU busy-cycles/SIMD ~= 50k constant across R4/R5/R6 -> packing idle
//    slots is the lever: 16-row waves halve the live set (acc[8]=32 regs) so
//    6 waves/SIMD fit (cap 85 >= est. live ~80; R1 lesson: never cap BELOW
//    the live set -- min-waves=4 on the 148-reg m=2 shape spilled 365 MB).
__global__ __launch_bounds__(256, 6) void snn_main(
    const u16* __restrict__ textBf, const u16* __restrict__ imageBf,
    const float* __restrict__ normT, const float* __restrict__ normI,
    const int* __restrict__ groups, const float* __restrict__ diagS,
    float* __restrict__ sameSum, float* __restrict__ totSum,
    unsigned int* __restrict__ doneCnt, float* __restrict__ out)
{
    const int lane = threadIdx.x & 63;
    const int w    = threadIdx.x >> 6;
    const int g    = lane >> 4;      // 16-lane group id (0..3)
    const int l15  = lane & 15;
    const int rowBase  = blockIdx.x * 64 + w * 16;
    const int colChunk = blockIdx.y * 256;

    // A fragments (16 image rows), resident for the whole wave
    short8 aFrag0 = *(const short8*)(imageBf + (rowBase + l15) * ND + g * 8);
    short8 aFrag1 = *(const short8*)(imageBf + (rowBase + l15) * ND + 32 + g * 8);

    // per-thread row metadata: row(r) = rowBase + g*4 + r  (C layout 16x16)
    float nI[4];
    int   gI[4];
    #pragma unroll
    for (int r = 0; r < 4; ++r) {
        int row = rowBase + g * 4 + r;
        nI[r] = normI[row];
        gI[r] = groups[row];
    }

    float sameAcc[4] = {0.f, 0.f, 0.f, 0.f};
    float totAcc[4]  = {0.f, 0.f, 0.f, 0.f};

    #pragma unroll
    for (int ct = 0; ct < 2; ++ct) {
        const int colBase = colChunk + ct * 128;

        float nT[8];
        int   gJ[8];
        f32x4 acc[8];
        #pragma unroll
        for (int n = 0; n < 8; ++n) {
            const int col = colBase + n * 16 + l15;
            nT[n] = normT[col];
            gJ[n] = groups[col];
            short8 b0 = *(const short8*)(textBf + col * ND + g * 8);
            short8 b1 = *(const short8*)(textBf + col * ND + 32 + g * 8);
            acc[n] = f32x4{0.f, 0.f, 0.f, 0.f};
            acc[n] = __builtin_amdgcn_mfma_f32_16x16x32_bf16(aFrag0, b0, acc[n], 0, 0, 0);
            acc[n] = __builtin_amdgcn_mfma_f32_16x16x32_bf16(aFrag1, b1, acc[n], 0, 0, 0);
        }

        // epilogue: d2K -> S -> predicated row accumulation
        #pragma unroll
        for (int n = 0; n < 8; ++n) {
            f32x4 c = acc[n];
            #pragma unroll
            for (int r = 0; r < 4; ++r) {
                float d2K = fmaf(M2K2, c[r], nI[r] + nT[n]);
                float s   = simval2(d2K);
                totAcc[r] += s;
                sameAcc[r] += (gI[r] == gJ[n]) ? s : 0.0f;
            }
        }
    }

    // reduce across the 16 lanes sharing each row, then one atomic per row
    #pragma unroll
    for (int r = 0; r < 4; ++r) {
        float sv = sameAcc[r];
        float tv = totAcc[r];
        #pragma unroll
        for (int mk = 8; mk >= 1; mk >>= 1) {
            sv += __shfl_xor(sv, mk, 64);
            tv += __shfl_xor(tv, mk, 64);
        }
        if (l15 == 0) {
            int row = rowBase + g * 4 + r;
            atomicAdd(&sameSum[row], sv);
            atomicAdd(&totSum[row], tv);
        }
    }

    // ---- fused finalize: last block to finish computes the scalar loss ----
    __shared__ int lastFlag;
    __shared__ float wsum[4];
    __syncthreads();                       // all waves' atomics issued
    if (threadIdx.x == 0) {
        __threadfence();                   // release: our atomics visible
        unsigned int old = atomicAdd(doneCnt, 1u);
        lastFlag = (old == TOTAL_BLOCKS - 1) ? 1 : 0;
    }
    __syncthreads();
    if (lastFlag) {
        __threadfence();                   // acquire side
        float partial = 0.0f;
        const int g0 = groups[0];
        for (int i = threadIdx.x; i < NB; i += 256) {
            float sameS = __hip_atomic_load(&sameSum[i], __ATOMIC_RELAXED,
                                            __HIP_MEMORY_SCOPE_AGENT);
            float tot   = __hip_atomic_load(&totSum[i], __ATOMIC_RELAXED,
                                            __HIP_MEMORY_SCOPE_AGENT);
            float diag  = diagS[i];
            float A = sameS - diag;            // same-group sum, j != i
            bool cond = (groups[i] == g0) && (i != 0);
            float num = cond ? A : (A + sameS);   // F == sameS
            float den = tot - sameS;
            bool valid = (num != 0.0f) && (den != 0.0f);
            float ratio = (valid ? num : 1.0f) / (valid ? den : 1.0f);
            partial += valid ? (-LN2 * __builtin_amdgcn_logf(ratio)) : 0.0f;
        }
        #pragma unroll
        for (int mk = 32; mk >= 1; mk >>= 1) partial += __shfl_xor(partial, mk, 64);
        if ((threadIdx.x & 63) == 0) wsum[threadIdx.x >> 6] = partial;
        __syncthreads();
        if (threadIdx.x == 0)
            out[0] = (wsum[0] + wsum[1] + wsum[2] + wsum[3]) * (1.0f / 8192.0f);
    }
}

// ---------------- launch ----------------------------------------------------
extern "C" void kernel_launch(void* const* d_in, const int* in_sizes, int n_in,
                              void* d_out, int out_size, void* d_ws, size_t ws_size,
                              hipStream_t stream) {
    const float* text  = (const float*)d_in[0];
    const float* image = (const float*)d_in[1];
    const int*   groups = (const int*)d_in[2];
    float* out = (float*)d_out;

    char* ws = (char*)d_ws;
    u16* textBf  = (u16*)ws;                          // 1 MB
    u16* imageBf = (u16*)(ws + (1 << 20));            // 1 MB
    float* normT   = (float*)(ws + (2 << 20));        // 32 KB each
    float* normI   = normT + NB;
    float* diagS   = normI + NB;
    float* sameSum = diagS + NB;
    float* totSum  = sameSum + NB;
    unsigned int* doneCnt = (unsigned int*)(totSum + NB);

    snn_prep<<<NB / 4, 256, 0, stream>>>(text, image, textBf, imageBf,
                                         normT, normI, diagS, sameSum, totSum,
                                         doneCnt, out);
    snn_main<<<dim3(GRID_X, GRID_Y), 256, 0, stream>>>(
        textBf, imageBf, normT, normI, groups, diagS,
        sameSum, totSum, doneCnt, out);
}

// Round 10
// 146.683 us; speedup vs baseline: 2.4564x; 2.4564x over previous
//
#include <hip/hip_runtime.h>
#include <hip/hip_bf16.h>
#include <math.h>

typedef unsigned short u16;
typedef unsigned int   u32;
typedef __attribute__((ext_vector_type(8))) short short8;   // 8 bf16 (4 VGPRs)
typedef __attribute__((ext_vector_type(4))) float f32x4;

#define NB 8192
#define ND 64
// dist scale: S = exp(-dist/0.05) = exp2(-K*dist), K = 20/ln2
// We carry K^2 inside d2 so that S = exp2(-sqrt(K2*d2)).
#define K2     832.5475634f      // (20/ln2)^2
#define M2K2  -1665.0951268f     // -2*K2
#define LN2    0.69314718055994531f

#define GRID_X 64
#define GRID_Y 32
#define TOTAL_BLOCKS (GRID_X * GRID_Y)

// S from pre-scaled squared distance (d2K = K2 * dist^2)
__device__ __forceinline__ float simval2(float d2K) {
    return __builtin_amdgcn_exp2f(-__builtin_amdgcn_sqrtf(fmaxf(d2K, 0.0f)));
}

// ---------------- prep: bf16 convert, packed norms, diagS, zero accums ------
// normTg/normIg carry the K2-scaled norm with the 7-bit group id stuffed into
// the low mantissa bits (rel. perturbation <= 2^-17 -> S rel err ~1e-5,
// far below the bf16 dot-product noise). Saves a separate group load + VGPR
// per column in the main loop.
__global__ __launch_bounds__(256) void snn_prep(
    const float* __restrict__ text, const float* __restrict__ image,
    const int* __restrict__ groups,
    u16* __restrict__ textBf, u16* __restrict__ imageBf,
    u32* __restrict__ normTg, u32* __restrict__ normIg,
    float* __restrict__ diagS, float* __restrict__ sameSum,
    float* __restrict__ totSum, unsigned int* __restrict__ doneCnt,
    float* __restrict__ out)
{
    const int lane = threadIdx.x & 63;
    const int row  = blockIdx.x * 4 + (threadIdx.x >> 6);
    const int idx  = row * ND + lane;

    float t  = text[idx];
    float im = image[idx];
    __hip_bfloat16 tb = __float2bfloat16(t);
    __hip_bfloat16 ib = __float2bfloat16(im);
    u16 tbits, ibits;
    __builtin_memcpy(&tbits, &tb, 2);
    __builtin_memcpy(&ibits, &ib, 2);
    textBf[idx]  = tbits;
    imageBf[idx] = ibits;

    float nt = t * t;
    float ni = im * im;
    float dp = __bfloat162float(tb) * __bfloat162float(ib); // match MFMA path
    #pragma unroll
    for (int m = 32; m >= 1; m >>= 1) {
        nt += __shfl_xor(nt, m, 64);
        ni += __shfl_xor(ni, m, 64);
        dp += __shfl_xor(dp, m, 64);
    }
    if (lane == 0) {
        float snt = K2 * nt;
        float sni = K2 * ni;
        u32 gg = (u32)groups[row] & 0x7Fu;
        normTg[row] = (__float_as_uint(snt) & ~0x7Fu) | gg;
        normIg[row] = (__float_as_uint(sni) & ~0x7Fu) | gg;
        float d2K = fmaf(M2K2, dp, sni + snt);  // K2 * dist(image_r, text_r)^2
        diagS[row] = simval2(d2K);
        sameSum[row] = 0.0f;
        totSum[row]  = 0.0f;
        if (row == 0) { *doneCnt = 0u; out[0] = 0.0f; }
    }
}

// ---------------- main: pairwise S + grouped row sums + fused finalize ------
// Grid: (64 row-tiles, 32 col-chunks) = 2048 blocks. Block: 256 thr = 4 waves.
// Block tile: 128 rows x 256 cols. Wave: 32 rows, acc[2][8] batch.
// HISTORY (invariants — keep):
//  - R4 (this shape, VGPR=104, natural alloc): 51.8 us, VALUBusy 39%. BEST.
//  - R5 (batch=1 transient): VGPR 32, zero load ILP -> 131 us. The 8-column
//    BATCH is the memory ILP; never shrink it.
//  - R6 (LDS staging): +22 us. Staging adds global latency + barrier without
//    removing it; direct L2 loads win at this reuse level.
//  - R1/R7 (launch_bounds min-waves 4 / 6): both SPILLED catastrophically
//    (365 MB / 535 MB scratch traffic). gfx950 occupancy is GRANULAR:
//    waves/SIMD = 8 at <=64 VGPR, 4 at 65..128, 2 at 129+. There is no 5/6.
//    A <=64-VGPR shape with real ILP is infeasible (acc+batch alone = 64).
//    => 4 waves/SIMD is the ceiling; NEVER set min-waves above 2.
//  - VALU busy-cycles/SIMD ~= 50k constant across shapes -> cut issue work.
__global__ __launch_bounds__(256, 2) void snn_main(
    const u16* __restrict__ textBf, const u16* __restrict__ imageBf,
    const u32* __restrict__ normTg, const u32* __restrict__ normIg,
    const int* __restrict__ groups, const float* __restrict__ diagS,
    float* __restrict__ sameSum, float* __restrict__ totSum,
    unsigned int* __restrict__ doneCnt, float* __restrict__ out)
{
    const int lane = threadIdx.x & 63;
    const int w    = threadIdx.x >> 6;
    const int g    = lane >> 4;      // 16-lane group id (0..3)
    const int l15  = lane & 15;
    const int rowBase  = blockIdx.x * 128 + w * 32;
    const int colChunk = blockIdx.y * 256;

    // A fragments (image rows), resident for the whole wave
    short8 aFrag[2][2];
    #pragma unroll
    for (int m = 0; m < 2; ++m)
        #pragma unroll
        for (int kk = 0; kk < 2; ++kk)
            aFrag[m][kk] = *(const short8*)(imageBf +
                (rowBase + m * 16 + l15) * ND + kk * 32 + g * 8);

    // per-thread row metadata: row(m,r) = rowBase + m*16 + g*4 + r
    float nI[2][4];
    int   gI[2][4];
    #pragma unroll
    for (int m = 0; m < 2; ++m)
        #pragma unroll
        for (int r = 0; r < 4; ++r) {
            u32 u = normIg[rowBase + m * 16 + g * 4 + r];
            nI[m][r] = __uint_as_float(u & ~0x7Fu);
            gI[m][r] = (int)(u & 0x7Fu);
        }

    float sameAcc[2][4];
    float totAcc[2][4];
    #pragma unroll
    for (int m = 0; m < 2; ++m)
        #pragma unroll
        for (int r = 0; r < 4; ++r) { sameAcc[m][r] = 0.0f; totAcc[m][r] = 0.0f; }

    #pragma unroll
    for (int ct = 0; ct < 2; ++ct) {
        const int colBase = colChunk + ct * 128;

        float nT[8];
        int   gJ[8];
        f32x4 acc[2][8];
        #pragma unroll
        for (int n = 0; n < 8; ++n) {
            const int col = colBase + n * 16 + l15;
            u32 uT = normTg[col];
            nT[n] = __uint_as_float(uT & ~0x7Fu);
            gJ[n] = (int)(uT & 0x7Fu);
            short8 b0 = *(const short8*)(textBf + col * ND + g * 8);
            short8 b1 = *(const short8*)(textBf + col * ND + 32 + g * 8);
            #pragma unroll
            for (int m = 0; m < 2; ++m) {
                acc[m][n] = f32x4{0.f, 0.f, 0.f, 0.f};
                acc[m][n] = __builtin_amdgcn_mfma_f32_16x16x32_bf16(
                                aFrag[m][0], b0, acc[m][n], 0, 0, 0);
                acc[m][n] = __builtin_amdgcn_mfma_f32_16x16x32_bf16(
                                aFrag[m][1], b1, acc[m][n], 0, 0, 0);
            }
        }

        // epilogue: d2K -> S -> predicated row accumulation
        #pragma unroll
        for (int m = 0; m < 2; ++m)
            #pragma unroll
            for (int n = 0; n < 8; ++n) {
                f32x4 c = acc[m][n];
                #pragma unroll
                for (int r = 0; r < 4; ++r) {
                    float d2K = fmaf(M2K2, c[r], nI[m][r] + nT[n]);
                    float s   = simval2(d2K);
                    totAcc[m][r] += s;
                    sameAcc[m][r] += (gI[m][r] == gJ[n]) ? s : 0.0f;
                }
            }
    }

    // reduce across the 16 lanes sharing each row, then one atomic per row
    #pragma unroll
    for (int m = 0; m < 2; ++m)
        #pragma unroll
        for (int r = 0; r < 4; ++r) {
            float sv = sameAcc[m][r];
            float tv = totAcc[m][r];
            #pragma unroll
            for (int mk = 8; mk >= 1; mk >>= 1) {
                sv += __shfl_xor(sv, mk, 64);
                tv += __shfl_xor(tv, mk, 64);
            }
            if (l15 == 0) {
                int row = rowBase + m * 16 + g * 4 + r;
                atomicAdd(&sameSum[row], sv);
                atomicAdd(&totSum[row], tv);
            }
        }

    // ---- fused finalize: last block to finish computes the scalar loss ----
    __shared__ int lastFlag;
    __shared__ float wsum[4];
    __syncthreads();                       // all waves' atomics issued
    if (threadIdx.x == 0) {
        __threadfence();                   // release: our atomics visible
        unsigned int old = atomicAdd(doneCnt, 1u);
        lastFlag = (old == TOTAL_BLOCKS - 1) ? 1 : 0;
    }
    __syncthreads();
    if (lastFlag) {
        __threadfence();                   // acquire side
        float partial = 0.0f;
        const int g0 = groups[0];
        for (int i = threadIdx.x; i < NB; i += 256) {
            float sameS = __hip_atomic_load(&sameSum[i], __ATOMIC_RELAXED,
                                            __HIP_MEMORY_SCOPE_AGENT);
            float tot   = __hip_atomic_load(&totSum[i], __ATOMIC_RELAXED,
                                            __HIP_MEMORY_SCOPE_AGENT);
            float diag  = diagS[i];
            float A = sameS - diag;            // same-group sum, j != i
            bool cond = (groups[i] == g0) && (i != 0);
            float num = cond ? A : (A + sameS);   // F == sameS
            float den = tot - sameS;
            bool valid = (num != 0.0f) && (den != 0.0f);
            float ratio = (valid ? num : 1.0f) / (valid ? den : 1.0f);
            partial += valid ? (-LN2 * __builtin_amdgcn_logf(ratio)) : 0.0f;
        }
        #pragma unroll
        for (int mk = 32; mk >= 1; mk >>= 1) partial += __shfl_xor(partial, mk, 64);
        if ((threadIdx.x & 63) == 0) wsum[threadIdx.x >> 6] = partial;
        __syncthreads();
        if (threadIdx.x == 0)
            out[0] = (wsum[0] + wsum[1] + wsum[2] + wsum[3]) * (1.0f / 8192.0f);
    }
}

// ---------------- launch ----------------------------------------------------
extern "C" void kernel_launch(void* const* d_in, const int* in_sizes, int n_in,
                              void* d_out, int out_size, void* d_ws, size_t ws_size,
                              hipStream_t stream) {
    const float* text  = (const float*)d_in[0];
    const float* image = (const float*)d_in[1];
    const int*   groups = (const int*)d_in[2];
    float* out = (float*)d_out;

    char* ws = (char*)d_ws;
    u16* textBf  = (u16*)ws;                          // 1 MB
    u16* imageBf = (u16*)(ws + (1 << 20));            // 1 MB
    u32* normTg  = (u32*)(ws + (2 << 20));            // 32 KB each
    u32* normIg  = normTg + NB;
    float* diagS   = (float*)(normIg + NB);
    float* sameSum = diagS + NB;
    float* totSum  = sameSum + NB;
    unsigned int* doneCnt = (unsigned int*)(totSum + NB);

    snn_prep<<<NB / 4, 256, 0, stream>>>(text, image, groups, textBf, imageBf,
                                         normTg, normIg, diagS, sameSum, totSum,
                                         doneCnt, out);
    snn_main<<<dim3(GRID_X, GRID_Y), 256, 0, stream>>>(
        textBf, imageBf, normTg, normIg, groups, diagS,
        sameSum, totSum, doneCnt, out);
}

// Round 11
// 115.716 us; speedup vs baseline: 3.1137x; 1.2676x over previous
//
#include <hip/hip_runtime.h>
#include <hip/hip_bf16.h>
#include <math.h>

typedef unsigned short u16;
typedef unsigned int   u32;
typedef __attribute__((ext_vector_type(8))) short short8;   // 8 bf16 (4 VGPRs)
typedef __attribute__((ext_vector_type(4))) float f32x4;

#define NB 8192
#define ND 64
// dist scale: S = exp(-dist/0.05) = exp2(-K*dist), K = 20/ln2
// We carry K^2 inside d2 so that S = exp2(-sqrt(K2*d2)).
#define K2     832.5475634f      // (20/ln2)^2
#define M2K2  -1665.0951268f     // -2*K2
#define LN2    0.69314718055994531f

#define GRID_X 64
#define GRID_Y 32

// S from pre-scaled squared distance (d2K = K2 * dist^2)
__device__ __forceinline__ float simval2(float d2K) {
    return __builtin_amdgcn_exp2f(-__builtin_amdgcn_sqrtf(fmaxf(d2K, 0.0f)));
}

// ---------------- prep: bf16 convert, packed norms, diagS, zero accums ------
// normTg/normIg carry the K2-scaled norm with the 7-bit group id stuffed into
// the low mantissa bits (rel. perturbation <= 2^-17 -> S rel err ~1e-5,
// far below the bf16 dot-product noise).
__global__ __launch_bounds__(256) void snn_prep(
    const float* __restrict__ text, const float* __restrict__ image,
    const int* __restrict__ groups,
    u16* __restrict__ textBf, u16* __restrict__ imageBf,
    u32* __restrict__ normTg, u32* __restrict__ normIg,
    float* __restrict__ diagS, float* __restrict__ sameSum,
    float* __restrict__ totSum, float* __restrict__ out)
{
    const int lane = threadIdx.x & 63;
    const int row  = blockIdx.x * 4 + (threadIdx.x >> 6);
    const int idx  = row * ND + lane;

    float t  = text[idx];
    float im = image[idx];
    __hip_bfloat16 tb = __float2bfloat16(t);
    __hip_bfloat16 ib = __float2bfloat16(im);
    u16 tbits, ibits;
    __builtin_memcpy(&tbits, &tb, 2);
    __builtin_memcpy(&ibits, &ib, 2);
    textBf[idx]  = tbits;
    imageBf[idx] = ibits;

    float nt = t * t;
    float ni = im * im;
    float dp = __bfloat162float(tb) * __bfloat162float(ib); // match MFMA path
    #pragma unroll
    for (int m = 32; m >= 1; m >>= 1) {
        nt += __shfl_xor(nt, m, 64);
        ni += __shfl_xor(ni, m, 64);
        dp += __shfl_xor(dp, m, 64);
    }
    if (lane == 0) {
        float snt = K2 * nt;
        float sni = K2 * ni;
        u32 gg = (u32)groups[row] & 0x7Fu;
        normTg[row] = (__float_as_uint(snt) & ~0x7Fu) | gg;
        normIg[row] = (__float_as_uint(sni) & ~0x7Fu) | gg;
        float d2K = fmaf(M2K2, dp, sni + snt);  // K2 * dist(image_r, text_r)^2
        diagS[row] = simval2(d2K);
        sameSum[row] = 0.0f;
        totSum[row]  = 0.0f;
        if (row == 0) out[0] = 0.0f;
    }
}

// ---------------- main: pairwise S + grouped row sums -----------------------
// Grid: (64 row-tiles, 32 col-chunks) = 2048 blocks. Block: 256 thr = 4 waves.
// Block tile: 128 rows x 256 cols. Wave: 32 rows, acc[2][8] batch.
// HISTORY (invariants — keep):
//  - R4 (this shape, separate finalize, VGPR=104): 51.8 us, VALUBusy 39%. BEST.
//  - R5 (batch=1 transient): VGPR 32, zero load ILP -> 131 us. The 8-column
//    BATCH is the memory ILP; never shrink it.
//  - R6 (LDS staging): regression mis-attributed to staging; carried the
//    fused-finalize tail too. Direct L2 loads still fine at this reuse level.
//  - R1/R7 (launch_bounds min-waves 4 / 6): both SPILLED catastrophically
//    (365/535 MB scratch). gfx950 occupancy is GRANULAR: 8 waves/SIMD at
//    <=64 VGPR, 4 at 65..128, 2 at 129+. NEVER set min-waves above 2.
//  - R10 (fused last-block finalize): +40 us idle. __threadfence before the
//    done-counter drains the block's contended row atomics ON the critical
//    path of every block (R4 left them fire-and-forget). NEVER fuse the
//    finalize via fence+counter; a separate 3-us dispatch is cheaper.
//  - VALU busy-cycles/SIMD ~= 50k constant across all shapes; wall time =
//    packing. Non-main ~55 us is fixed harness overhead (2 vs 3 kernels
//    identical) — not addressable here.
__global__ __launch_bounds__(256, 2) void snn_main(
    const u16* __restrict__ textBf, const u16* __restrict__ imageBf,
    const u32* __restrict__ normTg, const u32* __restrict__ normIg,
    float* __restrict__ sameSum, float* __restrict__ totSum)
{
    const int lane = threadIdx.x & 63;
    const int w    = threadIdx.x >> 6;
    const int g    = lane >> 4;      // 16-lane group id (0..3)
    const int l15  = lane & 15;
    const int rowBase  = blockIdx.x * 128 + w * 32;
    const int colChunk = blockIdx.y * 256;

    // A fragments (image rows), resident for the whole wave
    short8 aFrag[2][2];
    #pragma unroll
    for (int m = 0; m < 2; ++m)
        #pragma unroll
        for (int kk = 0; kk < 2; ++kk)
            aFrag[m][kk] = *(const short8*)(imageBf +
                (rowBase + m * 16 + l15) * ND + kk * 32 + g * 8);

    // per-thread row metadata: row(m,r) = rowBase + m*16 + g*4 + r
    float nI[2][4];
    int   gI[2][4];
    #pragma unroll
    for (int m = 0; m < 2; ++m)
        #pragma unroll
        for (int r = 0; r < 4; ++r) {
            u32 u = normIg[rowBase + m * 16 + g * 4 + r];
            nI[m][r] = __uint_as_float(u & ~0x7Fu);
            gI[m][r] = (int)(u & 0x7Fu);
        }

    float sameAcc[2][4];
    float totAcc[2][4];
    #pragma unroll
    for (int m = 0; m < 2; ++m)
        #pragma unroll
        for (int r = 0; r < 4; ++r) { sameAcc[m][r] = 0.0f; totAcc[m][r] = 0.0f; }

    #pragma unroll
    for (int ct = 0; ct < 2; ++ct) {
        const int colBase = colChunk + ct * 128;

        float nT[8];
        int   gJ[8];
        f32x4 acc[2][8];
        #pragma unroll
        for (int n = 0; n < 8; ++n) {
            const int col = colBase + n * 16 + l15;
            u32 uT = normTg[col];
            nT[n] = __uint_as_float(uT & ~0x7Fu);
            gJ[n] = (int)(uT & 0x7Fu);
            short8 b0 = *(const short8*)(textBf + col * ND + g * 8);
            short8 b1 = *(const short8*)(textBf + col * ND + 32 + g * 8);
            #pragma unroll
            for (int m = 0; m < 2; ++m) {
                acc[m][n] = f32x4{0.f, 0.f, 0.f, 0.f};
                acc[m][n] = __builtin_amdgcn_mfma_f32_16x16x32_bf16(
                                aFrag[m][0], b0, acc[m][n], 0, 0, 0);
                acc[m][n] = __builtin_amdgcn_mfma_f32_16x16x32_bf16(
                                aFrag[m][1], b1, acc[m][n], 0, 0, 0);
            }
        }

        // epilogue: d2K -> S -> predicated row accumulation
        #pragma unroll
        for (int m = 0; m < 2; ++m)
            #pragma unroll
            for (int n = 0; n < 8; ++n) {
                f32x4 c = acc[m][n];
                #pragma unroll
                for (int r = 0; r < 4; ++r) {
                    float d2K = fmaf(M2K2, c[r], nI[m][r] + nT[n]);
                    float s   = simval2(d2K);
                    totAcc[m][r] += s;
                    sameAcc[m][r] += (gI[m][r] == gJ[n]) ? s : 0.0f;
                }
            }
    }

    // reduce across the 16 lanes sharing each row, then one atomic per row
    // (fire-and-forget: completion overlaps across blocks — R10 lesson)
    #pragma unroll
    for (int m = 0; m < 2; ++m)
        #pragma unroll
        for (int r = 0; r < 4; ++r) {
            float sv = sameAcc[m][r];
            float tv = totAcc[m][r];
            #pragma unroll
            for (int mk = 8; mk >= 1; mk >>= 1) {
                sv += __shfl_xor(sv, mk, 64);
                tv += __shfl_xor(tv, mk, 64);
            }
            if (l15 == 0) {
                int row = rowBase + m * 16 + g * 4 + r;
                atomicAdd(&sameSum[row], sv);
                atomicAdd(&totSum[row], tv);
            }
        }
}

// ---------------- finalize: per-row loss + scalar reduction -----------------
__global__ __launch_bounds__(256) void snn_finalize(
    const float* __restrict__ sameSum, const float* __restrict__ totSum,
    const float* __restrict__ diagS, const int* __restrict__ groups,
    float* __restrict__ out)
{
    const int i = blockIdx.x * 256 + threadIdx.x;
    float sameS = sameSum[i];
    float tot   = totSum[i];
    float diag  = diagS[i];
    float A = sameS - diag;            // same-group sum, j != i
    int g0 = groups[0];
    bool cond = (groups[i] == g0) && (i != 0);
    float num = cond ? A : (A + sameS);   // F == sameS
    float den = tot - sameS;
    bool valid = (num != 0.0f) && (den != 0.0f);
    float ratio = (valid ? num : 1.0f) / (valid ? den : 1.0f);
    float per = valid ? (-LN2 * __builtin_amdgcn_logf(ratio)) : 0.0f;

    float v = per;
    #pragma unroll
    for (int mk = 32; mk >= 1; mk >>= 1) v += __shfl_xor(v, mk, 64);
    __shared__ float wsum[4];
    if ((threadIdx.x & 63) == 0) wsum[threadIdx.x >> 6] = v;
    __syncthreads();
    if (threadIdx.x == 0) {
        float s = wsum[0] + wsum[1] + wsum[2] + wsum[3];
        atomicAdd(out, s * (1.0f / 8192.0f));
    }
}

// ---------------- launch ----------------------------------------------------
extern "C" void kernel_launch(void* const* d_in, const int* in_sizes, int n_in,
                              void* d_out, int out_size, void* d_ws, size_t ws_size,
                              hipStream_t stream) {
    const float* text  = (const float*)d_in[0];
    const float* image = (const float*)d_in[1];
    const int*   groups = (const int*)d_in[2];
    float* out = (float*)d_out;

    char* ws = (char*)d_ws;
    u16* textBf  = (u16*)ws;                          // 1 MB
    u16* imageBf = (u16*)(ws + (1 << 20));            // 1 MB
    u32* normTg  = (u32*)(ws + (2 << 20));            // 32 KB each
    u32* normIg  = normTg + NB;
    float* diagS   = (float*)(normIg + NB);
    float* sameSum = diagS + NB;
    float* totSum  = sameSum + NB;

    snn_prep<<<NB / 4, 256, 0, stream>>>(text, image, groups, textBf, imageBf,
                                         normTg, normIg, diagS, sameSum, totSum,
                                         out);
    snn_main<<<dim3(GRID_X, GRID_Y), 256, 0, stream>>>(
        textBf, imageBf, normTg, normIg, sameSum, totSum);
    snn_finalize<<<NB / 256, 256, 0, stream>>>(sameSum, totSum, diagS, groups, out);
}